// Round 14
// baseline (323.932 us; speedup 1.0000x reference)
//
#include <hip/hip_runtime.h>
#include <stdint.h>

typedef __attribute__((ext_vector_type(8))) short bf16x8;
typedef __attribute__((ext_vector_type(4))) float f32x4;
typedef __attribute__((ext_vector_type(2))) float f32x2;

#define NF 256
#define NH 256
#define KTOT 512
#define BM 128
#define BK 64
#define EB 512   // edge blocks for bucket sort (2 blocks/CU)
#define NBIN 512 // high-bit buckets (dst>>8), covers 131072 >= 100000 nodes

static __device__ __forceinline__ unsigned short f2bf(float f){
  union { float f; unsigned int u; } v; v.f = f;
  unsigned int r = v.u + 0x7fffu + ((v.u >> 16) & 1u);   // RNE
  return (unsigned short)(r >> 16);
}
// f32 -> OCP e4m3fn (RNE, FTZ below 2^-6, saturate at 448)
static __device__ __forceinline__ unsigned int f2e4(float f){
  union { float f; unsigned int u; } v; v.f = f;
  unsigned int s = v.u >> 31;
  unsigned int mag = v.u & 0x7fffffffu;
  if (mag > 0x43E00000u) mag = 0x43E00000u;             // clamp to 448
  unsigned int r = mag + 0x7ffffu + ((mag >> 20) & 1u); // RNE at 3 mantissa bits
  if (r < 0x3C800000u) return 0u;                       // below 2^-6 -> 0
  return (s << 7) | (((r >> 20) - 960u) & 0x7fu);
}
// fp8x4 -> 4 bf16 (lossless: e4m3 subset of bf16)
static __device__ __forceinline__ ushort4 dec8(unsigned int v){
#if __has_builtin(__builtin_amdgcn_cvt_pk_f32_fp8)
  f32x2 lo = __builtin_amdgcn_cvt_pk_f32_fp8((int)v, false);
  f32x2 hi = __builtin_amdgcn_cvt_pk_f32_fp8((int)v, true);
  ushort4 o; o.x=f2bf(lo[0]); o.y=f2bf(lo[1]); o.z=f2bf(hi[0]); o.w=f2bf(hi[1]);
  return o;
#else
  ushort4 o; unsigned short r[4];
  #pragma unroll
  for (int j = 0; j < 4; j++){
    unsigned int b = (v >> (8*j)) & 0xffu;
    unsigned int tt = b & 0x7fu;
    union { unsigned int u; float f; } w;
    w.u = ((tt + 960u) << 20) | ((b & 0x80u) << 24);
    r[j] = tt ? f2bf(w.f) : (unsigned short)0;
  }
  o.x=r[0]; o.y=r[1]; o.z=r[2]; o.w=r[3];
  return o;
#endif
}
// fp8 word -> two packed f32x2 accumulates (v_cvt_pk + v_pk_add)
static __device__ __forceinline__ void accw(unsigned int v, f32x2& a, f32x2& b){
#if __has_builtin(__builtin_amdgcn_cvt_pk_f32_fp8)
  a += __builtin_amdgcn_cvt_pk_f32_fp8((int)v, false);
  b += __builtin_amdgcn_cvt_pk_f32_fp8((int)v, true);
#else
  #pragma unroll
  for (int j = 0; j < 4; j++){
    unsigned int bb = (v >> (8*j)) & 0xffu;
    unsigned int tt = bb & 0x7fu;
    union { unsigned int u; float f; } w;
    w.u = ((tt + 960u) << 20) | ((bb & 0x80u) << 24);
    float f = tt ? w.f : 0.f;
    if (j==0) a[0] += f; else if (j==1) a[1] += f; else if (j==2) b[0] += f; else b[1] += f;
  }
#endif
}
// pack two f32x2 -> fp8x4 word
static __device__ __forceinline__ unsigned int pkw(f32x2 a, f32x2 b){
#if __has_builtin(__builtin_amdgcn_cvt_pk_fp8_f32)
  int t = __builtin_amdgcn_cvt_pk_fp8_f32(a[0], a[1], 0, false);
  t = __builtin_amdgcn_cvt_pk_fp8_f32(b[0], b[1], t, true);
  return (unsigned int)t;
#else
  return f2e4(a[0]) | (f2e4(a[1])<<8) | (f2e4(b[0])<<16) | (f2e4(b[1])<<24);
#endif
}
// async global->LDS 16B: lds_wave_base is wave-uniform; HW adds lane*16
static __device__ __forceinline__ void gload16(const void* g, void* lds_wave_base, int lane){
#if __has_builtin(__builtin_amdgcn_global_load_lds)
  __builtin_amdgcn_global_load_lds(
      (const __attribute__((address_space(1))) unsigned int*)g,
      (__attribute__((address_space(3))) unsigned int*)lds_wave_base, 16, 0, 0);
  (void)lane;
#else
  *(int4*)((char*)lds_wave_base + (size_t)lane*16) = *(const int4*)g;
#endif
}

// ---- K1: fused independent prep work.
//      Blocks [0,2048):    x f32 -> bf16 xb + ROW-MAJOR fp8 xq
//      Blocks [2048,2560): Wt[n][k] = bf16 of (k<256 ? Ws[k][n] : Wn[k-256][n])
//      Blocks [2560,3072): 512-bin LDS histogram of edst>>8 -> H[bin*EB + blk]
__global__ void __launch_bounds__(256) k_cvt(const float* __restrict__ x,
                      unsigned short* __restrict__ xb,
                      unsigned int* __restrict__ xq, int n8,
                      const float* __restrict__ Ws, const float* __restrict__ Wn,
                      unsigned short* __restrict__ Wt,
                      const int* __restrict__ edst, int* __restrict__ H, int ne){
  if (blockIdx.x < 2048){
    for (int i = blockIdx.x*blockDim.x + threadIdx.x; i < n8; i += 2048*blockDim.x){
      const float4* p = (const float4*)(x + (size_t)i*8);
      float4 a = p[0], b = p[1];
      ushort4 o0, o1;
      o0.x=f2bf(a.x); o0.y=f2bf(a.y); o0.z=f2bf(a.z); o0.w=f2bf(a.w);
      o1.x=f2bf(b.x); o1.y=f2bf(b.y); o1.z=f2bf(b.z); o1.w=f2bf(b.w);
      ushort4* q = (ushort4*)(xb + (size_t)i*8);
      q[0] = o0; q[1] = o1;
      unsigned int w0 = f2e4(a.x) | (f2e4(a.y)<<8) | (f2e4(a.z)<<16) | (f2e4(a.w)<<24);
      unsigned int w1 = f2e4(b.x) | (f2e4(b.y)<<8) | (f2e4(b.z)<<16) | (f2e4(b.w)<<24);
      uint2 o; o.x = w0; o.y = w1;
      ((uint2*)xq)[i] = o;
    }
  } else if (blockIdx.x < 2560){
    int t = (blockIdx.x - 2048)*blockDim.x + threadIdx.x;
    if (t < NH*KTOT){
      int n = t >> 9, k = t & 511;
      float v = (k < NF) ? Ws[(size_t)k*NH + n] : Wn[(size_t)(k-NF)*NH + n];
      Wt[t] = (unsigned short)f2bf(v);
    }
  } else {
    __shared__ int lh[NBIN];
    int blk = blockIdx.x - 2560, t = threadIdx.x;
    for (int i = t; i < NBIN; i += 256) lh[i] = 0;
    __syncthreads();
    int chunk = (ne + EB - 1) / EB;
    int e0 = blk * chunk, e1 = ne < e0 + chunk ? ne : e0 + chunk;
    for (int e = e0 + t; e < e1; e += 256)
      atomicAdd(&lh[((unsigned)edst[e]) >> 8], 1);
    __syncthreads();
    for (int i = t; i < NBIN; i += 256) H[i*EB + blk] = lh[i];
  }
}

// ---- K4a: per-block (1024-chunk) sums ----
__global__ void k_partial(const int* __restrict__ deg, int* __restrict__ partial, int n){
  __shared__ int sm[256];
  int b = blockIdx.x, t = threadIdx.x;
  int i0 = b*1024 + t*4;
  int s = 0;
  if (i0 + 3 < n){ int4 v = *(const int4*)(deg + i0); s = v.x+v.y+v.z+v.w; }
  else { for (int j=0;j<4;j++) if (i0+j < n) s += deg[i0+j]; }
  sm[t] = s; __syncthreads();
  for (int d = 128; d > 0; d >>= 1){ if (t < d) sm[t] += sm[t+d]; __syncthreads(); }
  if (t == 0) partial[b] = sm[0];
}

// ---- K4b: exclusive scan of partials (1 block of 256; nb <= 256) ----
__global__ void k_scanp(int* __restrict__ partial, int nb){
  __shared__ int sm[256];
  int t = threadIdx.x;
  int v = (t < nb) ? partial[t] : 0;
  sm[t] = v; __syncthreads();
  for (int d = 1; d < 256; d <<= 1){
    int u = (t >= d) ? sm[t-d] : 0; __syncthreads();
    sm[t] += u; __syncthreads();
  }
  if (t < nb) partial[t] = sm[t] - v;
}

// ---- K4c: apply scan -> exclusive prefix ----
__global__ void k_scanapply(const int* __restrict__ deg, const int* __restrict__ partial,
                            int* __restrict__ off, int n, int ne){
  __shared__ int sm[256];
  int b = blockIdx.x, t = threadIdx.x;
  int i0 = b*1024 + t*4;
  int d0=0,d1=0,d2=0,d3=0;
  if (i0 + 3 < n){ int4 v = *(const int4*)(deg + i0); d0=v.x; d1=v.y; d2=v.z; d3=v.w; }
  else { if(i0<n)d0=deg[i0]; if(i0+1<n)d1=deg[i0+1]; if(i0+2<n)d2=deg[i0+2]; if(i0+3<n)d3=deg[i0+3]; }
  int s = d0+d1+d2+d3;
  sm[t] = s; __syncthreads();
  for (int d = 1; d < 256; d <<= 1){
    int u = (t >= d) ? sm[t-d] : 0; __syncthreads();
    sm[t] += u; __syncthreads();
  }
  int run = partial[b] + sm[t] - s;
  if (i0   < n) off[i0]   = run; run += d0;
  if (i0+1 < n) off[i0+1] = run; run += d1;
  if (i0+2 < n) off[i0+2] = run; run += d2;
  if (i0+3 < n) off[i0+3] = run;
  if (b == 0 && t == 0) off[n] = ne;
}

// ---- S3: scatter edges to buckets, rank via LDS atomics; payload (src<<8)|(dst&255) ----
__global__ void __launch_bounds__(256) k_bscat(const int* __restrict__ src,
                                               const int* __restrict__ dst,
                                               const int* __restrict__ base,
                                               unsigned int* __restrict__ bkt, int ne){
  __shared__ int lc[NBIN];
  __shared__ int lb[NBIN];
  int blk = blockIdx.x, t = threadIdx.x;
  for (int i = t; i < NBIN; i += 256){ lc[i] = 0; lb[i] = base[i*EB + blk]; }
  __syncthreads();
  int chunk = (ne + EB - 1) / EB;
  int e0 = blk * chunk, e1 = ne < e0 + chunk ? ne : e0 + chunk;
  for (int e = e0 + t; e < e1; e += 256){
    int d = dst[e];
    int bin = ((unsigned)d) >> 8;
    int p = lb[bin] + atomicAdd(&lc[bin], 1);
    bkt[p] = (((unsigned)src[e]) << 8) | ((unsigned)d & 255u);
  }
}

// ---- S4: one block per bucket -> exact CSR (off, col), all-LDS binning ----
__global__ void __launch_bounds__(256) k_csr(const unsigned int* __restrict__ bkt,
                                             const int* __restrict__ base,
                                             int* __restrict__ off, int* __restrict__ col,
                                             int nn, int ne){
  __shared__ int lh[256], sc[256], se[256], lc[256];
  int b = blockIdx.x, t = threadIdx.x;
  int n0 = base[b*EB], n1 = base[(b+1)*EB];
  lh[t] = 0; lc[t] = 0;
  __syncthreads();
  for (int e = n0 + t; e < n1; e += 256)
    atomicAdd(&lh[bkt[e] & 255u], 1);
  __syncthreads();
  int v = lh[t];
  sc[t] = v; __syncthreads();
  for (int d = 1; d < 256; d <<= 1){
    int u = (t >= d) ? sc[t-d] : 0; __syncthreads();
    sc[t] += u; __syncthreads();
  }
  int excl = sc[t] - v;
  se[t] = excl;
  int node = b*256 + t;
  if (node <= nn) off[node] = n0 + excl;
  __syncthreads();
  for (int e = n0 + t; e < n1; e += 256){
    unsigned u = bkt[e];
    int low = (int)(u & 255u);
    int r = atomicAdd(&lc[low], 1);
    col[n0 + se[low] + r] = (int)(u >> 8);
  }
}

// ---- K6 (v2, r8): pull-aggregation over row-major fp8 x; wave/node; scalar-base, 16-deep ----
__global__ void __launch_bounds__(256) k_agg(const unsigned int* __restrict__ xw,
                                             const int* __restrict__ off,
                                             const int* __restrict__ col,
                                             unsigned int* __restrict__ hq, int n){
  int w = threadIdx.x >> 6;
  int lane = threadIdx.x & 63;
  int node = blockIdx.x*4 + w;
  if (node >= n) return;
  int e0 = off[node], e1 = off[node+1];
  int deg = e1 - e0;
  f32x2 alo = (f32x2){0.f,0.f}, ahi = (f32x2){0.f,0.f};
  for (int c0 = 0; c0 < deg; c0 += 64){
    int len = deg - c0; if (len > 64) len = 64;
    int cv = 0;
    if (lane < len) cv = col[e0 + c0 + lane];   // one vector load covers 64 edges
    int i = 0;
    for (; i + 16 <= len; i += 16){
      unsigned int u[16];
      #pragma unroll
      for (int j = 0; j < 16; j++){
        int s = __builtin_amdgcn_readlane(cv, i + j);
        u[j] = xw[(size_t)s*64 + lane];
      }
      #pragma unroll
      for (int j = 0; j < 16; j++) accw(u[j], alo, ahi);
    }
    for (; i + 4 <= len; i += 4){
      unsigned int u[4];
      #pragma unroll
      for (int j = 0; j < 4; j++){
        int s = __builtin_amdgcn_readlane(cv, i + j);
        u[j] = xw[(size_t)s*64 + lane];
      }
      #pragma unroll
      for (int j = 0; j < 4; j++) accw(u[j], alo, ahi);
    }
    for (; i < len; ++i){
      int s = __builtin_amdgcn_readlane(cv, i);
      unsigned int u0 = xw[(size_t)s*64 + lane];
      accw(u0, alo, ahi);
    }
  }
  float inv = 1.f / (float)(deg > 1 ? deg : 1);
  alo *= inv; ahi *= inv;
  hq[(size_t)node*64 + lane] = pkw(alo, ahi);
}

// ---- K7 v2: out = relu([xb, hq] @ Wt^T + b) ----
// 2-phase pipelined: As double-buffered (2x16KB), stage(t+1) issued BEFORE MFMA(t),
// ONE barrier per K-step. B read directly from global (Wt is 0.5MB, L2-resident) --
// no Bs staging, no second barrier. 8 waves (2m x 4n), 64x64 out per wave.
__global__ void __launch_bounds__(512, 4) k_gemm(const unsigned short* __restrict__ xb,
                                                 const unsigned char*  __restrict__ hq,
                                                 const unsigned short* __restrict__ Wt,
                                                 const float* __restrict__ bias,
                                                 float* __restrict__ out, int M){
  __shared__ __align__(16) unsigned short As[2][BM*BK];   // 2 x 16 KB
  int t = threadIdx.x;
  int m0 = blockIdx.x * BM;
  int w = t >> 6, lane = t & 63;
  int wm = w >> 2, wn = w & 3;
  int lrow = lane & 15;
  int cgrp = (lane >> 4) * 16;     // byte col group within 128B row
  int k8   = (lane >> 4) * 8;      // element col group for B fragment
  int slot = t & 7;                // staging 16B slot within row

  f32x4 acc[4][4];
  #pragma unroll
  for (int i=0;i<4;i++)
    #pragma unroll
    for (int j=0;j<4;j++) acc[i][j] = (f32x4){0.f,0.f,0.f,0.f};

  auto stageA = [&](int kk, int buf){
    if (kk < NF){
      // self half: direct global->LDS, source address pre-swizzled
      #pragma unroll
      for (int p = 0; p < 2; p++){
        int flat = p*512 + t;
        int row = flat >> 3;
        const char* g = (const char*)(xb + (size_t)(m0 + row)*NF + kk)
                        + ((slot ^ (row & 7)) << 4);
        gload16(g, (char*)As[buf] + (size_t)(flat & ~63)*16, lane);
      }
    } else {
      // neigh half: fp8 -> bf16 reg-stage into swizzled LDS position
      #pragma unroll
      for (int p = 0; p < 2; p++){
        int flat = p*512 + t;
        int row = flat >> 3;
        const unsigned char* g = hq + (size_t)(m0 + row)*NF + (kk - NF)
                                 + ((slot ^ (row & 7)) << 3);
        uint2 v = *(const uint2*)g;
        ushort4 lo = dec8(v.x), hi = dec8(v.y);
        char* dstb = (char*)As[buf] + (size_t)row*128 + slot*16;
        *(ushort4*)dstb = lo;
        *(ushort4*)(dstb + 8) = hi;
      }
    }
  };

  stageA(0, 0);
  __syncthreads();           // As[0] ready

  int cur = 0;
  for (int kk = 0; kk < KTOT; kk += BK){
    if (kk + BK < KTOT) stageA(kk + BK, cur ^ 1);   // issue next-tile loads early
    #pragma unroll
    for (int ks = 0; ks < 2; ks++){
      bf16x8 af[4], bfr[4];
      #pragma unroll
      for (int mi=0;mi<4;mi++){
        int row = wm*64 + mi*16 + lrow;
        int cb = (ks*64 + cgrp) ^ ((row & 7) << 4);
        af[mi] = *(const bf16x8*)((const char*)As[cur] + (size_t)row*128 + cb);
      }
      #pragma unroll
      for (int ni=0;ni<4;ni++){
        int row = wn*64 + ni*16 + lrow;
        bfr[ni] = *(const bf16x8*)(Wt + (size_t)row*KTOT + kk + ks*32 + k8);
      }
      #pragma unroll
      for (int mi=0;mi<4;mi++)
        #pragma unroll
        for (int ni=0;ni<4;ni++)
          acc[mi][ni] = __builtin_amdgcn_mfma_f32_16x16x32_bf16(af[mi], bfr[ni], acc[mi][ni], 0, 0, 0);
    }
    __syncthreads();         // drains stage of next tile (had full MFMA phase to land)
    cur ^= 1;
  }

  #pragma unroll
  for (int ni=0;ni<4;ni++){
    int cn = wn*64 + ni*16 + lrow;
    float bv = bias[cn];
    #pragma unroll
    for (int mi=0;mi<4;mi++){
      #pragma unroll
      for (int r=0;r<4;r++){
        int rm = m0 + wm*64 + mi*16 + (lane>>4)*4 + r;
        if (rm < M){
          float v = acc[mi][ni][r] + bv;
          out[(size_t)rm*NH + cn] = v > 0.f ? v : 0.f;
        }
      }
    }
  }
}

extern "C" void kernel_launch(void* const* d_in, const int* in_sizes, int n_in,
                              void* d_out, int out_size, void* d_ws, size_t ws_size,
                              hipStream_t stream){
  const float* x      = (const float*)d_in[0];
  const float* Wself  = (const float*)d_in[1];
  const float* Wneigh = (const float*)d_in[2];
  const float* bias   = (const float*)d_in[3];
  const int*   esrc   = (const int*)d_in[4];
  const int*   edst   = (const int*)d_in[5];
  const int nn = in_sizes[0] / NF;   // 100000
  const int ne = in_sizes[4];        // 3200000
  const int mpad = ((nn + BM - 1) / BM) * BM;  // 100096

  // workspace carve-up (~112 MiB; hq aliases bkt; H aliases col -- both dead before use)
  char* w = (char*)d_ws;
  auto alloc = [&](size_t bytes)->char*{
    char* p = w; w += (bytes + 511) & ~size_t(511); return p;
  };
  unsigned short* xb  = (unsigned short*)alloc((size_t)mpad*NF*2); // bf16 x, 51.25 MB
  unsigned char*  xq  = (unsigned char*)alloc((size_t)nn*NF);      // fp8 x row-major, 25.6 MB
  char* hq_bkt        = alloc((size_t)mpad*NF);                    // union: bkt (12.8) / hq (25.6)
  int* col            = (int*)alloc((size_t)ne*4);                 // CSR col 12.8 MB; first 1MB doubles as H
  int* base           = (int*)alloc(((size_t)NBIN*EB + 1)*4);      // scanned hist, 1.05 MB
  int* off            = (int*)alloc((size_t)(nn+1)*4);
  unsigned short* Wt  = (unsigned short*)alloc((size_t)NH*KTOT*2);
  int* partial        = (int*)alloc(4096);
  unsigned int* bkt   = (unsigned int*)hq_bkt;
  unsigned char* hq   = (unsigned char*)hq_bkt;
  int* H              = col;   // H dead after k_scanapply; col written only in k_csr

  const int nH = NBIN*EB;            // 262144
  const int nb = nH / 1024;          // 256

  k_cvt<<<2048 + 512 + 512, 256, 0, stream>>>(x, xb, (unsigned int*)xq, nn*NF/8,
                                              Wself, Wneigh, Wt, edst, H, ne);
  k_partial<<<nb, 256, 0, stream>>>(H, partial, nH);
  k_scanp<<<1, 256, 0, stream>>>(partial, nb);
  k_scanapply<<<nb, 256, 0, stream>>>(H, partial, base, nH, ne);
  k_bscat<<<EB, 256, 0, stream>>>(esrc, edst, base, bkt, ne);
  k_csr<<<NBIN, 256, 0, stream>>>(bkt, base, off, col, nn, ne);
  k_agg<<<(nn + 3)/4, 256, 0, stream>>>((const unsigned int*)xq, off, col, (unsigned int*)hq, nn);
  k_gemm<<<mpad/BM, 512, 0, stream>>>(xb, hq, Wt, bias, (float*)d_out, nn);
}

// Round 15
// 318.159 us; speedup vs baseline: 1.0181x; 1.0181x over previous
//
#include <hip/hip_runtime.h>
#include <stdint.h>

typedef __attribute__((ext_vector_type(8))) short bf16x8;
typedef __attribute__((ext_vector_type(4))) float f32x4;
typedef __attribute__((ext_vector_type(2))) float f32x2;

#define NF 256
#define NH 256
#define KTOT 512
#define BM 128
#define BK 64
#define EB 512   // edge blocks for bucket sort (2 blocks/CU)
#define NBIN 512 // high-bit buckets (dst>>8), covers 131072 >= 100000 nodes

static __device__ __forceinline__ unsigned short f2bf(float f){
  union { float f; unsigned int u; } v; v.f = f;
  unsigned int r = v.u + 0x7fffu + ((v.u >> 16) & 1u);   // RNE
  return (unsigned short)(r >> 16);
}
// f32 -> OCP e4m3fn (RNE, FTZ below 2^-6, saturate at 448)
static __device__ __forceinline__ unsigned int f2e4(float f){
  union { float f; unsigned int u; } v; v.f = f;
  unsigned int s = v.u >> 31;
  unsigned int mag = v.u & 0x7fffffffu;
  if (mag > 0x43E00000u) mag = 0x43E00000u;             // clamp to 448
  unsigned int r = mag + 0x7ffffu + ((mag >> 20) & 1u); // RNE at 3 mantissa bits
  if (r < 0x3C800000u) return 0u;                       // below 2^-6 -> 0
  return (s << 7) | (((r >> 20) - 960u) & 0x7fu);
}
// fp8x4 -> 4 bf16 (lossless: e4m3 subset of bf16)
static __device__ __forceinline__ ushort4 dec8(unsigned int v){
#if __has_builtin(__builtin_amdgcn_cvt_pk_f32_fp8)
  f32x2 lo = __builtin_amdgcn_cvt_pk_f32_fp8((int)v, false);
  f32x2 hi = __builtin_amdgcn_cvt_pk_f32_fp8((int)v, true);
  ushort4 o; o.x=f2bf(lo[0]); o.y=f2bf(lo[1]); o.z=f2bf(hi[0]); o.w=f2bf(hi[1]);
  return o;
#else
  ushort4 o; unsigned short r[4];
  #pragma unroll
  for (int j = 0; j < 4; j++){
    unsigned int b = (v >> (8*j)) & 0xffu;
    unsigned int tt = b & 0x7fu;
    union { unsigned int u; float f; } w;
    w.u = ((tt + 960u) << 20) | ((b & 0x80u) << 24);
    r[j] = tt ? f2bf(w.f) : (unsigned short)0;
  }
  o.x=r[0]; o.y=r[1]; o.z=r[2]; o.w=r[3];
  return o;
#endif
}
// fp8 word -> two packed f32x2 accumulates (v_cvt_pk + v_pk_add)
static __device__ __forceinline__ void accw(unsigned int v, f32x2& a, f32x2& b){
#if __has_builtin(__builtin_amdgcn_cvt_pk_f32_fp8)
  a += __builtin_amdgcn_cvt_pk_f32_fp8((int)v, false);
  b += __builtin_amdgcn_cvt_pk_f32_fp8((int)v, true);
#else
  #pragma unroll
  for (int j = 0; j < 4; j++){
    unsigned int bb = (v >> (8*j)) & 0xffu;
    unsigned int tt = bb & 0x7fu;
    union { unsigned int u; float f; } w;
    w.u = ((tt + 960u) << 20) | ((bb & 0x80u) << 24);
    float f = tt ? w.f : 0.f;
    if (j==0) a[0] += f; else if (j==1) a[1] += f; else if (j==2) b[0] += f; else b[1] += f;
  }
#endif
}
// pack two f32x2 -> fp8x4 word
static __device__ __forceinline__ unsigned int pkw(f32x2 a, f32x2 b){
#if __has_builtin(__builtin_amdgcn_cvt_pk_fp8_f32)
  int t = __builtin_amdgcn_cvt_pk_fp8_f32(a[0], a[1], 0, false);
  t = __builtin_amdgcn_cvt_pk_fp8_f32(b[0], b[1], t, true);
  return (unsigned int)t;
#else
  return f2e4(a[0]) | (f2e4(a[1])<<8) | (f2e4(b[0])<<16) | (f2e4(b[1])<<24);
#endif
}
// async global->LDS 16B: lds_wave_base is wave-uniform; HW adds lane*16
static __device__ __forceinline__ void gload16(const void* g, void* lds_wave_base, int lane){
#if __has_builtin(__builtin_amdgcn_global_load_lds)
  __builtin_amdgcn_global_load_lds(
      (const __attribute__((address_space(1))) unsigned int*)g,
      (__attribute__((address_space(3))) unsigned int*)lds_wave_base, 16, 0, 0);
  (void)lane;
#else
  *(int4*)((char*)lds_wave_base + (size_t)lane*16) = *(const int4*)g;
#endif
}

// ---- K1: fused independent prep work.
//      Blocks [0,2048):    x f32 -> bf16 xb + ROW-MAJOR fp8 xq
//      Blocks [2048,2560): Wt[n][k] = bf16 of (k<256 ? Ws[k][n] : Wn[k-256][n])
//      Blocks [2560,3072): 512-bin LDS histogram of edst>>8 -> H[bin*EB + blk]
__global__ void __launch_bounds__(256) k_cvt(const float* __restrict__ x,
                      unsigned short* __restrict__ xb,
                      unsigned int* __restrict__ xq, int n8,
                      const float* __restrict__ Ws, const float* __restrict__ Wn,
                      unsigned short* __restrict__ Wt,
                      const int* __restrict__ edst, int* __restrict__ H, int ne){
  if (blockIdx.x < 2048){
    for (int i = blockIdx.x*blockDim.x + threadIdx.x; i < n8; i += 2048*blockDim.x){
      const float4* p = (const float4*)(x + (size_t)i*8);
      float4 a = p[0], b = p[1];
      ushort4 o0, o1;
      o0.x=f2bf(a.x); o0.y=f2bf(a.y); o0.z=f2bf(a.z); o0.w=f2bf(a.w);
      o1.x=f2bf(b.x); o1.y=f2bf(b.y); o1.z=f2bf(b.z); o1.w=f2bf(b.w);
      ushort4* q = (ushort4*)(xb + (size_t)i*8);
      q[0] = o0; q[1] = o1;
      unsigned int w0 = f2e4(a.x) | (f2e4(a.y)<<8) | (f2e4(a.z)<<16) | (f2e4(a.w)<<24);
      unsigned int w1 = f2e4(b.x) | (f2e4(b.y)<<8) | (f2e4(b.z)<<16) | (f2e4(b.w)<<24);
      uint2 o; o.x = w0; o.y = w1;
      ((uint2*)xq)[i] = o;
    }
  } else if (blockIdx.x < 2560){
    int t = (blockIdx.x - 2048)*blockDim.x + threadIdx.x;
    if (t < NH*KTOT){
      int n = t >> 9, k = t & 511;
      float v = (k < NF) ? Ws[(size_t)k*NH + n] : Wn[(size_t)(k-NF)*NH + n];
      Wt[t] = (unsigned short)f2bf(v);
    }
  } else {
    __shared__ int lh[NBIN];
    int blk = blockIdx.x - 2560, t = threadIdx.x;
    for (int i = t; i < NBIN; i += 256) lh[i] = 0;
    __syncthreads();
    int chunk = (ne + EB - 1) / EB;
    int e0 = blk * chunk, e1 = ne < e0 + chunk ? ne : e0 + chunk;
    for (int e = e0 + t; e < e1; e += 256)
      atomicAdd(&lh[((unsigned)edst[e]) >> 8], 1);
    __syncthreads();
    for (int i = t; i < NBIN; i += 256) H[i*EB + blk] = lh[i];
  }
}

// ---- K4a: per-block (1024-chunk) sums ----
__global__ void k_partial(const int* __restrict__ deg, int* __restrict__ partial, int n){
  __shared__ int sm[256];
  int b = blockIdx.x, t = threadIdx.x;
  int i0 = b*1024 + t*4;
  int s = 0;
  if (i0 + 3 < n){ int4 v = *(const int4*)(deg + i0); s = v.x+v.y+v.z+v.w; }
  else { for (int j=0;j<4;j++) if (i0+j < n) s += deg[i0+j]; }
  sm[t] = s; __syncthreads();
  for (int d = 128; d > 0; d >>= 1){ if (t < d) sm[t] += sm[t+d]; __syncthreads(); }
  if (t == 0) partial[b] = sm[0];
}

// ---- K4b: exclusive scan of partials (1 block of 256; nb <= 256) ----
__global__ void k_scanp(int* __restrict__ partial, int nb){
  __shared__ int sm[256];
  int t = threadIdx.x;
  int v = (t < nb) ? partial[t] : 0;
  sm[t] = v; __syncthreads();
  for (int d = 1; d < 256; d <<= 1){
    int u = (t >= d) ? sm[t-d] : 0; __syncthreads();
    sm[t] += u; __syncthreads();
  }
  if (t < nb) partial[t] = sm[t] - v;
}

// ---- K4c: apply scan -> exclusive prefix ----
__global__ void k_scanapply(const int* __restrict__ deg, const int* __restrict__ partial,
                            int* __restrict__ off, int n, int ne){
  __shared__ int sm[256];
  int b = blockIdx.x, t = threadIdx.x;
  int i0 = b*1024 + t*4;
  int d0=0,d1=0,d2=0,d3=0;
  if (i0 + 3 < n){ int4 v = *(const int4*)(deg + i0); d0=v.x; d1=v.y; d2=v.z; d3=v.w; }
  else { if(i0<n)d0=deg[i0]; if(i0+1<n)d1=deg[i0+1]; if(i0+2<n)d2=deg[i0+2]; if(i0+3<n)d3=deg[i0+3]; }
  int s = d0+d1+d2+d3;
  sm[t] = s; __syncthreads();
  for (int d = 1; d < 256; d <<= 1){
    int u = (t >= d) ? sm[t-d] : 0; __syncthreads();
    sm[t] += u; __syncthreads();
  }
  int run = partial[b] + sm[t] - s;
  if (i0   < n) off[i0]   = run; run += d0;
  if (i0+1 < n) off[i0+1] = run; run += d1;
  if (i0+2 < n) off[i0+2] = run; run += d2;
  if (i0+3 < n) off[i0+3] = run;
  if (b == 0 && t == 0) off[n] = ne;
}

// ---- S3: scatter edges to buckets, rank via LDS atomics; payload (src<<8)|(dst&255) ----
__global__ void __launch_bounds__(256) k_bscat(const int* __restrict__ src,
                                               const int* __restrict__ dst,
                                               const int* __restrict__ base,
                                               unsigned int* __restrict__ bkt, int ne){
  __shared__ int lc[NBIN];
  __shared__ int lb[NBIN];
  int blk = blockIdx.x, t = threadIdx.x;
  for (int i = t; i < NBIN; i += 256){ lc[i] = 0; lb[i] = base[i*EB + blk]; }
  __syncthreads();
  int chunk = (ne + EB - 1) / EB;
  int e0 = blk * chunk, e1 = ne < e0 + chunk ? ne : e0 + chunk;
  for (int e = e0 + t; e < e1; e += 256){
    int d = dst[e];
    int bin = ((unsigned)d) >> 8;
    int p = lb[bin] + atomicAdd(&lc[bin], 1);
    bkt[p] = (((unsigned)src[e]) << 8) | ((unsigned)d & 255u);
  }
}

// ---- S4: one block per bucket -> exact CSR (off, col), all-LDS binning ----
__global__ void __launch_bounds__(256) k_csr(const unsigned int* __restrict__ bkt,
                                             const int* __restrict__ base,
                                             int* __restrict__ off, int* __restrict__ col,
                                             int nn, int ne){
  __shared__ int lh[256], sc[256], se[256], lc[256];
  int b = blockIdx.x, t = threadIdx.x;
  int n0 = base[b*EB], n1 = base[(b+1)*EB];
  lh[t] = 0; lc[t] = 0;
  __syncthreads();
  for (int e = n0 + t; e < n1; e += 256)
    atomicAdd(&lh[bkt[e] & 255u], 1);
  __syncthreads();
  int v = lh[t];
  sc[t] = v; __syncthreads();
  for (int d = 1; d < 256; d <<= 1){
    int u = (t >= d) ? sc[t-d] : 0; __syncthreads();
    sc[t] += u; __syncthreads();
  }
  int excl = sc[t] - v;
  se[t] = excl;
  int node = b*256 + t;
  if (node <= nn) off[node] = n0 + excl;
  __syncthreads();
  for (int e = n0 + t; e < n1; e += 256){
    unsigned u = bkt[e];
    int low = (int)(u & 255u);
    int r = atomicAdd(&lc[low], 1);
    col[n0 + se[low] + r] = (int)(u >> 8);
  }
}

// ---- K6 (v2, r8): pull-aggregation over row-major fp8 x; wave/node; scalar-base, 16-deep ----
__global__ void __launch_bounds__(256) k_agg(const unsigned int* __restrict__ xw,
                                             const int* __restrict__ off,
                                             const int* __restrict__ col,
                                             unsigned int* __restrict__ hq, int n){
  int w = threadIdx.x >> 6;
  int lane = threadIdx.x & 63;
  int node = blockIdx.x*4 + w;
  if (node >= n) return;
  int e0 = off[node], e1 = off[node+1];
  int deg = e1 - e0;
  f32x2 alo = (f32x2){0.f,0.f}, ahi = (f32x2){0.f,0.f};
  for (int c0 = 0; c0 < deg; c0 += 64){
    int len = deg - c0; if (len > 64) len = 64;
    int cv = 0;
    if (lane < len) cv = col[e0 + c0 + lane];   // one vector load covers 64 edges
    int i = 0;
    for (; i + 16 <= len; i += 16){
      unsigned int u[16];
      #pragma unroll
      for (int j = 0; j < 16; j++){
        int s = __builtin_amdgcn_readlane(cv, i + j);
        u[j] = xw[(size_t)s*64 + lane];
      }
      #pragma unroll
      for (int j = 0; j < 16; j++) accw(u[j], alo, ahi);
    }
    for (; i + 4 <= len; i += 4){
      unsigned int u[4];
      #pragma unroll
      for (int j = 0; j < 4; j++){
        int s = __builtin_amdgcn_readlane(cv, i + j);
        u[j] = xw[(size_t)s*64 + lane];
      }
      #pragma unroll
      for (int j = 0; j < 4; j++) accw(u[j], alo, ahi);
    }
    for (; i < len; ++i){
      int s = __builtin_amdgcn_readlane(cv, i);
      unsigned int u0 = xw[(size_t)s*64 + lane];
      accw(u0, alo, ahi);
    }
  }
  float inv = 1.f / (float)(deg > 1 ? deg : 1);
  alo *= inv; ahi *= inv;
  hq[(size_t)node*64 + lane] = pkw(alo, ahi);
}

// ---- K7 v3: out = relu([xb, hq] @ Wt^T + b) ----
// As double-buffered (one barrier/K-step); B pipelined in REGISTERS a half-step
// ahead so no MFMA ever waits on a just-issued load (T3/T4 discipline: MFMA reads
// only LDS + pre-loaded regs). 8 waves (2m x 4n), 64x64 out per wave.
__global__ void __launch_bounds__(512, 4) k_gemm(const unsigned short* __restrict__ xb,
                                                 const unsigned char*  __restrict__ hq,
                                                 const unsigned short* __restrict__ Wt,
                                                 const float* __restrict__ bias,
                                                 float* __restrict__ out, int M){
  __shared__ __align__(16) unsigned short As[2][BM*BK];   // 2 x 16 KB
  int t = threadIdx.x;
  int m0 = blockIdx.x * BM;
  int w = t >> 6, lane = t & 63;
  int wm = w >> 2, wn = w & 3;
  int lrow = lane & 15;
  int cgrp = (lane >> 4) * 16;     // byte col group within 128B row
  int k8   = (lane >> 4) * 8;      // element col group for B fragment
  int slot = t & 7;                // staging 16B slot within row

  // per-wave B base: row = wn*64 + ni*16 + lrow
  const unsigned short* Wbase = Wt + (size_t)(wn*64 + lrow)*KTOT + k8;

  f32x4 acc[4][4];
  #pragma unroll
  for (int i=0;i<4;i++)
    #pragma unroll
    for (int j=0;j<4;j++) acc[i][j] = (f32x4){0.f,0.f,0.f,0.f};

  auto stageA = [&](int kk, int buf){
    if (kk < NF){
      #pragma unroll
      for (int p = 0; p < 2; p++){
        int flat = p*512 + t;
        int row = flat >> 3;
        const char* g = (const char*)(xb + (size_t)(m0 + row)*NF + kk)
                        + ((slot ^ (row & 7)) << 4);
        gload16(g, (char*)As[buf] + (size_t)(flat & ~63)*16, lane);
      }
    } else {
      #pragma unroll
      for (int p = 0; p < 2; p++){
        int flat = p*512 + t;
        int row = flat >> 3;
        const unsigned char* g = hq + (size_t)(m0 + row)*NF + (kk - NF)
                                 + ((slot ^ (row & 7)) << 3);
        uint2 v = *(const uint2*)g;
        ushort4 lo = dec8(v.x), hi = dec8(v.y);
        char* dstb = (char*)As[buf] + (size_t)row*128 + slot*16;
        *(ushort4*)dstb = lo;
        *(ushort4*)(dstb + 8) = hi;
      }
    }
  };
  auto ldB = [&](bf16x8* dst, int kk, int ks){
    #pragma unroll
    for (int ni = 0; ni < 4; ni++)
      dst[ni] = *(const bf16x8*)(Wbase + (size_t)ni*16*KTOT + kk + ks*32);
  };
  auto mfma8 = [&](int buf, int ks, const bf16x8* bfr){
    bf16x8 af[4];
    #pragma unroll
    for (int mi=0;mi<4;mi++){
      int row = wm*64 + mi*16 + lrow;
      int cb = (ks*64 + cgrp) ^ ((row & 7) << 4);
      af[mi] = *(const bf16x8*)((const char*)As[buf] + (size_t)row*128 + cb);
    }
    #pragma unroll
    for (int mi=0;mi<4;mi++)
      #pragma unroll
      for (int ni=0;ni<4;ni++)
        acc[mi][ni] = __builtin_amdgcn_mfma_f32_16x16x32_bf16(af[mi], bfr[ni], acc[mi][ni], 0, 0, 0);
  };

  bf16x8 B0[4], B1[4];
  stageA(0, 0);
  ldB(B0, 0, 0);
  __syncthreads();           // As[0] + B0 ready

  int cur = 0;
  #pragma unroll
  for (int kk = 0; kk < KTOT; kk += BK){
    ldB(B1, kk, 1);                                   // ks=1 operands in flight
    if (kk + BK < KTOT) stageA(kk + BK, cur ^ 1);     // next A tile in flight
    mfma8(cur, 0, B0);                                // B0 already resident
    if (kk + BK < KTOT) ldB(B0, kk + BK, 0);          // next step's ks=0 operands
    mfma8(cur, 1, B1);                                // covered by ks0's 16 MFMAs
    __syncthreads();                                  // drains stage (had MFMA time)
    cur ^= 1;
  }

  #pragma unroll
  for (int ni=0;ni<4;ni++){
    int cn = wn*64 + ni*16 + lrow;
    float bv = bias[cn];
    #pragma unroll
    for (int mi=0;mi<4;mi++){
      #pragma unroll
      for (int r=0;r<4;r++){
        int rm = m0 + wm*64 + mi*16 + (lane>>4)*4 + r;
        if (rm < M){
          float v = acc[mi][ni][r] + bv;
          out[(size_t)rm*NH + cn] = v > 0.f ? v : 0.f;
        }
      }
    }
  }
}

extern "C" void kernel_launch(void* const* d_in, const int* in_sizes, int n_in,
                              void* d_out, int out_size, void* d_ws, size_t ws_size,
                              hipStream_t stream){
  const float* x      = (const float*)d_in[0];
  const float* Wself  = (const float*)d_in[1];
  const float* Wneigh = (const float*)d_in[2];
  const float* bias   = (const float*)d_in[3];
  const int*   esrc   = (const int*)d_in[4];
  const int*   edst   = (const int*)d_in[5];
  const int nn = in_sizes[0] / NF;   // 100000
  const int ne = in_sizes[4];        // 3200000
  const int mpad = ((nn + BM - 1) / BM) * BM;  // 100096

  // workspace carve-up (~112 MiB; hq aliases bkt; H aliases col -- both dead before use)
  char* w = (char*)d_ws;
  auto alloc = [&](size_t bytes)->char*{
    char* p = w; w += (bytes + 511) & ~size_t(511); return p;
  };
  unsigned short* xb  = (unsigned short*)alloc((size_t)mpad*NF*2); // bf16 x, 51.25 MB
  unsigned char*  xq  = (unsigned char*)alloc((size_t)nn*NF);      // fp8 x row-major, 25.6 MB
  char* hq_bkt        = alloc((size_t)mpad*NF);                    // union: bkt (12.8) / hq (25.6)
  int* col            = (int*)alloc((size_t)ne*4);                 // CSR col 12.8 MB; first 1MB doubles as H
  int* base           = (int*)alloc(((size_t)NBIN*EB + 1)*4);      // scanned hist, 1.05 MB
  int* off            = (int*)alloc((size_t)(nn+1)*4);
  unsigned short* Wt  = (unsigned short*)alloc((size_t)NH*KTOT*2);
  int* partial        = (int*)alloc(4096);
  unsigned int* bkt   = (unsigned int*)hq_bkt;
  unsigned char* hq   = (unsigned char*)hq_bkt;
  int* H              = col;   // H dead after k_scanapply; col written only in k_csr

  const int nH = NBIN*EB;            // 262144
  const int nb = nH / 1024;          // 256

  k_cvt<<<2048 + 512 + 512, 256, 0, stream>>>(x, xb, (unsigned int*)xq, nn*NF/8,
                                              Wself, Wneigh, Wt, edst, H, ne);
  k_partial<<<nb, 256, 0, stream>>>(H, partial, nH);
  k_scanp<<<1, 256, 0, stream>>>(partial, nb);
  k_scanapply<<<nb, 256, 0, stream>>>(H, partial, base, nH, ne);
  k_bscat<<<EB, 256, 0, stream>>>(esrc, edst, base, bkt, ne);
  k_csr<<<NBIN, 256, 0, stream>>>(bkt, base, off, col, nn, ne);
  k_agg<<<(nn + 3)/4, 256, 0, stream>>>((const unsigned int*)xq, off, col, (unsigned int*)hq, nn);
  k_gemm<<<mpad/BM, 512, 0, stream>>>(xb, hq, Wt, bias, (float*)d_out, nn);
}

// Round 16
// 299.308 us; speedup vs baseline: 1.0823x; 1.0630x over previous
//
#include <hip/hip_runtime.h>
#include <stdint.h>

typedef __attribute__((ext_vector_type(8))) short bf16x8;
typedef __attribute__((ext_vector_type(4))) float f32x4;
typedef __attribute__((ext_vector_type(2))) float f32x2;

#define NF 256
#define NH 256
#define KTOT 512
#define BM 128
#define BN 128
#define BK 64
#define EB 512   // edge blocks for bucket sort (2 blocks/CU)
#define NBIN 512 // high-bit buckets (dst>>8), covers 131072 >= 100000 nodes

static __device__ __forceinline__ unsigned short f2bf(float f){
  union { float f; unsigned int u; } v; v.f = f;
  unsigned int r = v.u + 0x7fffu + ((v.u >> 16) & 1u);   // RNE
  return (unsigned short)(r >> 16);
}
// f32 -> OCP e4m3fn (RNE, FTZ below 2^-6, saturate at 448)
static __device__ __forceinline__ unsigned int f2e4(float f){
  union { float f; unsigned int u; } v; v.f = f;
  unsigned int s = v.u >> 31;
  unsigned int mag = v.u & 0x7fffffffu;
  if (mag > 0x43E00000u) mag = 0x43E00000u;             // clamp to 448
  unsigned int r = mag + 0x7ffffu + ((mag >> 20) & 1u); // RNE at 3 mantissa bits
  if (r < 0x3C800000u) return 0u;                       // below 2^-6 -> 0
  return (s << 7) | (((r >> 20) - 960u) & 0x7fu);
}
// fp8x4 -> 4 bf16 (lossless: e4m3 subset of bf16)
static __device__ __forceinline__ ushort4 dec8(unsigned int v){
#if __has_builtin(__builtin_amdgcn_cvt_pk_f32_fp8)
  f32x2 lo = __builtin_amdgcn_cvt_pk_f32_fp8((int)v, false);
  f32x2 hi = __builtin_amdgcn_cvt_pk_f32_fp8((int)v, true);
  ushort4 o; o.x=f2bf(lo[0]); o.y=f2bf(lo[1]); o.z=f2bf(hi[0]); o.w=f2bf(hi[1]);
  return o;
#else
  ushort4 o; unsigned short r[4];
  #pragma unroll
  for (int j = 0; j < 4; j++){
    unsigned int b = (v >> (8*j)) & 0xffu;
    unsigned int tt = b & 0x7fu;
    union { unsigned int u; float f; } w;
    w.u = ((tt + 960u) << 20) | ((b & 0x80u) << 24);
    r[j] = tt ? f2bf(w.f) : (unsigned short)0;
  }
  o.x=r[0]; o.y=r[1]; o.z=r[2]; o.w=r[3];
  return o;
#endif
}
// fp8 word -> two packed f32x2 accumulates (v_cvt_pk + v_pk_add)
static __device__ __forceinline__ void accw(unsigned int v, f32x2& a, f32x2& b){
#if __has_builtin(__builtin_amdgcn_cvt_pk_f32_fp8)
  a += __builtin_amdgcn_cvt_pk_f32_fp8((int)v, false);
  b += __builtin_amdgcn_cvt_pk_f32_fp8((int)v, true);
#else
  #pragma unroll
  for (int j = 0; j < 4; j++){
    unsigned int bb = (v >> (8*j)) & 0xffu;
    unsigned int tt = bb & 0x7fu;
    union { unsigned int u; float f; } w;
    w.u = ((tt + 960u) << 20) | ((bb & 0x80u) << 24);
    float f = tt ? w.f : 0.f;
    if (j==0) a[0] += f; else if (j==1) a[1] += f; else if (j==2) b[0] += f; else b[1] += f;
  }
#endif
}
// pack two f32x2 -> fp8x4 word
static __device__ __forceinline__ unsigned int pkw(f32x2 a, f32x2 b){
#if __has_builtin(__builtin_amdgcn_cvt_pk_fp8_f32)
  int t = __builtin_amdgcn_cvt_pk_fp8_f32(a[0], a[1], 0, false);
  t = __builtin_amdgcn_cvt_pk_fp8_f32(b[0], b[1], t, true);
  return (unsigned int)t;
#else
  return f2e4(a[0]) | (f2e4(a[1])<<8) | (f2e4(b[0])<<16) | (f2e4(b[1])<<24);
#endif
}
// async global->LDS 16B: lds_wave_base is wave-uniform; HW adds lane*16
static __device__ __forceinline__ void gload16(const void* g, void* lds_wave_base, int lane){
#if __has_builtin(__builtin_amdgcn_global_load_lds)
  __builtin_amdgcn_global_load_lds(
      (const __attribute__((address_space(1))) unsigned int*)g,
      (__attribute__((address_space(3))) unsigned int*)lds_wave_base, 16, 0, 0);
  (void)lane;
#else
  *(int4*)((char*)lds_wave_base + (size_t)lane*16) = *(const int4*)g;
#endif
}

// ---- K1: fused independent prep work.
//      Blocks [0,2048):    x f32 -> bf16 xb + ROW-MAJOR fp8 xq
//      Blocks [2048,2560): Wt[n][k] = bf16 of (k<256 ? Ws[k][n] : Wn[k-256][n])
//      Blocks [2560,3072): 512-bin LDS histogram of edst>>8 -> H[bin*EB + blk]
__global__ void __launch_bounds__(256) k_cvt(const float* __restrict__ x,
                      unsigned short* __restrict__ xb,
                      unsigned int* __restrict__ xq, int n8,
                      const float* __restrict__ Ws, const float* __restrict__ Wn,
                      unsigned short* __restrict__ Wt,
                      const int* __restrict__ edst, int* __restrict__ H, int ne){
  if (blockIdx.x < 2048){
    for (int i = blockIdx.x*blockDim.x + threadIdx.x; i < n8; i += 2048*blockDim.x){
      const float4* p = (const float4*)(x + (size_t)i*8);
      float4 a = p[0], b = p[1];
      ushort4 o0, o1;
      o0.x=f2bf(a.x); o0.y=f2bf(a.y); o0.z=f2bf(a.z); o0.w=f2bf(a.w);
      o1.x=f2bf(b.x); o1.y=f2bf(b.y); o1.z=f2bf(b.z); o1.w=f2bf(b.w);
      ushort4* q = (ushort4*)(xb + (size_t)i*8);
      q[0] = o0; q[1] = o1;
      unsigned int w0 = f2e4(a.x) | (f2e4(a.y)<<8) | (f2e4(a.z)<<16) | (f2e4(a.w)<<24);
      unsigned int w1 = f2e4(b.x) | (f2e4(b.y)<<8) | (f2e4(b.z)<<16) | (f2e4(b.w)<<24);
      uint2 o; o.x = w0; o.y = w1;
      ((uint2*)xq)[i] = o;
    }
  } else if (blockIdx.x < 2560){
    int t = (blockIdx.x - 2048)*blockDim.x + threadIdx.x;
    if (t < NH*KTOT){
      int n = t >> 9, k = t & 511;
      float v = (k < NF) ? Ws[(size_t)k*NH + n] : Wn[(size_t)(k-NF)*NH + n];
      Wt[t] = (unsigned short)f2bf(v);
    }
  } else {
    __shared__ int lh[NBIN];
    int blk = blockIdx.x - 2560, t = threadIdx.x;
    for (int i = t; i < NBIN; i += 256) lh[i] = 0;
    __syncthreads();
    int chunk = (ne + EB - 1) / EB;
    int e0 = blk * chunk, e1 = ne < e0 + chunk ? ne : e0 + chunk;
    for (int e = e0 + t; e < e1; e += 256)
      atomicAdd(&lh[((unsigned)edst[e]) >> 8], 1);
    __syncthreads();
    for (int i = t; i < NBIN; i += 256) H[i*EB + blk] = lh[i];
  }
}

// ---- K4a: per-block (1024-chunk) sums ----
__global__ void k_partial(const int* __restrict__ deg, int* __restrict__ partial, int n){
  __shared__ int sm[256];
  int b = blockIdx.x, t = threadIdx.x;
  int i0 = b*1024 + t*4;
  int s = 0;
  if (i0 + 3 < n){ int4 v = *(const int4*)(deg + i0); s = v.x+v.y+v.z+v.w; }
  else { for (int j=0;j<4;j++) if (i0+j < n) s += deg[i0+j]; }
  sm[t] = s; __syncthreads();
  for (int d = 128; d > 0; d >>= 1){ if (t < d) sm[t] += sm[t+d]; __syncthreads(); }
  if (t == 0) partial[b] = sm[0];
}

// ---- K4b: exclusive scan of partials (1 block of 256; nb <= 256) ----
__global__ void k_scanp(int* __restrict__ partial, int nb){
  __shared__ int sm[256];
  int t = threadIdx.x;
  int v = (t < nb) ? partial[t] : 0;
  sm[t] = v; __syncthreads();
  for (int d = 1; d < 256; d <<= 1){
    int u = (t >= d) ? sm[t-d] : 0; __syncthreads();
    sm[t] += u; __syncthreads();
  }
  if (t < nb) partial[t] = sm[t] - v;
}

// ---- K4c: apply scan -> exclusive prefix ----
__global__ void k_scanapply(const int* __restrict__ deg, const int* __restrict__ partial,
                            int* __restrict__ off, int n, int ne){
  __shared__ int sm[256];
  int b = blockIdx.x, t = threadIdx.x;
  int i0 = b*1024 + t*4;
  int d0=0,d1=0,d2=0,d3=0;
  if (i0 + 3 < n){ int4 v = *(const int4*)(deg + i0); d0=v.x; d1=v.y; d2=v.z; d3=v.w; }
  else { if(i0<n)d0=deg[i0]; if(i0+1<n)d1=deg[i0+1]; if(i0+2<n)d2=deg[i0+2]; if(i0+3<n)d3=deg[i0+3]; }
  int s = d0+d1+d2+d3;
  sm[t] = s; __syncthreads();
  for (int d = 1; d < 256; d <<= 1){
    int u = (t >= d) ? sm[t-d] : 0; __syncthreads();
    sm[t] += u; __syncthreads();
  }
  int run = partial[b] + sm[t] - s;
  if (i0   < n) off[i0]   = run; run += d0;
  if (i0+1 < n) off[i0+1] = run; run += d1;
  if (i0+2 < n) off[i0+2] = run; run += d2;
  if (i0+3 < n) off[i0+3] = run;
  if (b == 0 && t == 0) off[n] = ne;
}

// ---- S3: scatter edges to buckets, rank via LDS atomics; payload (src<<8)|(dst&255) ----
__global__ void __launch_bounds__(256) k_bscat(const int* __restrict__ src,
                                               const int* __restrict__ dst,
                                               const int* __restrict__ base,
                                               unsigned int* __restrict__ bkt, int ne){
  __shared__ int lc[NBIN];
  __shared__ int lb[NBIN];
  int blk = blockIdx.x, t = threadIdx.x;
  for (int i = t; i < NBIN; i += 256){ lc[i] = 0; lb[i] = base[i*EB + blk]; }
  __syncthreads();
  int chunk = (ne + EB - 1) / EB;
  int e0 = blk * chunk, e1 = ne < e0 + chunk ? ne : e0 + chunk;
  for (int e = e0 + t; e < e1; e += 256){
    int d = dst[e];
    int bin = ((unsigned)d) >> 8;
    int p = lb[bin] + atomicAdd(&lc[bin], 1);
    bkt[p] = (((unsigned)src[e]) << 8) | ((unsigned)d & 255u);
  }
}

// ---- S4: one block per bucket -> exact CSR (off, col), all-LDS binning ----
__global__ void __launch_bounds__(256) k_csr(const unsigned int* __restrict__ bkt,
                                             const int* __restrict__ base,
                                             int* __restrict__ off, int* __restrict__ col,
                                             int nn, int ne){
  __shared__ int lh[256], sc[256], se[256], lc[256];
  int b = blockIdx.x, t = threadIdx.x;
  int n0 = base[b*EB], n1 = base[(b+1)*EB];
  lh[t] = 0; lc[t] = 0;
  __syncthreads();
  for (int e = n0 + t; e < n1; e += 256)
    atomicAdd(&lh[bkt[e] & 255u], 1);
  __syncthreads();
  int v = lh[t];
  sc[t] = v; __syncthreads();
  for (int d = 1; d < 256; d <<= 1){
    int u = (t >= d) ? sc[t-d] : 0; __syncthreads();
    sc[t] += u; __syncthreads();
  }
  int excl = sc[t] - v;
  se[t] = excl;
  int node = b*256 + t;
  if (node <= nn) off[node] = n0 + excl;
  __syncthreads();
  for (int e = n0 + t; e < n1; e += 256){
    unsigned u = bkt[e];
    int low = (int)(u & 255u);
    int r = atomicAdd(&lc[low], 1);
    col[n0 + se[low] + r] = (int)(u >> 8);
  }
}

// ---- K6 (v2, r8): pull-aggregation over row-major fp8 x; wave/node; scalar-base, 16-deep ----
__global__ void __launch_bounds__(256) k_agg(const unsigned int* __restrict__ xw,
                                             const int* __restrict__ off,
                                             const int* __restrict__ col,
                                             unsigned int* __restrict__ hq, int n){
  int w = threadIdx.x >> 6;
  int lane = threadIdx.x & 63;
  int node = blockIdx.x*4 + w;
  if (node >= n) return;
  int e0 = off[node], e1 = off[node+1];
  int deg = e1 - e0;
  f32x2 alo = (f32x2){0.f,0.f}, ahi = (f32x2){0.f,0.f};
  for (int c0 = 0; c0 < deg; c0 += 64){
    int len = deg - c0; if (len > 64) len = 64;
    int cv = 0;
    if (lane < len) cv = col[e0 + c0 + lane];   // one vector load covers 64 edges
    int i = 0;
    for (; i + 16 <= len; i += 16){
      unsigned int u[16];
      #pragma unroll
      for (int j = 0; j < 16; j++){
        int s = __builtin_amdgcn_readlane(cv, i + j);
        u[j] = xw[(size_t)s*64 + lane];
      }
      #pragma unroll
      for (int j = 0; j < 16; j++) accw(u[j], alo, ahi);
    }
    for (; i + 4 <= len; i += 4){
      unsigned int u[4];
      #pragma unroll
      for (int j = 0; j < 4; j++){
        int s = __builtin_amdgcn_readlane(cv, i + j);
        u[j] = xw[(size_t)s*64 + lane];
      }
      #pragma unroll
      for (int j = 0; j < 4; j++) accw(u[j], alo, ahi);
    }
    for (; i < len; ++i){
      int s = __builtin_amdgcn_readlane(cv, i);
      unsigned int u0 = xw[(size_t)s*64 + lane];
      accw(u0, alo, ahi);
    }
  }
  float inv = 1.f / (float)(deg > 1 ? deg : 1);
  alo *= inv; ahi *= inv;
  hq[(size_t)node*64 + lane] = pkw(alo, ahi);
}

// ---- K7 v4 (m97-replica): out = relu([xb, hq] @ Wt^T + b) ----
// 256 threads = 4 waves (2m x 2n), BM=BN=128, BK=64; single-buffered As+Bs (32 KB),
// 2 barriers/K-step; gload_lds + XOR-swizzled source. Grid 2 x 782 = 1564 blocks
// (~4 resident/CU) -- TLP covers barrier drains (r14 showed 1 block/CU was the stall).
__global__ void __launch_bounds__(256, 4) k_gemm(const unsigned short* __restrict__ xb,
                                                 const unsigned char*  __restrict__ hq,
                                                 const unsigned short* __restrict__ Wt,
                                                 const float* __restrict__ bias,
                                                 float* __restrict__ out, int M){
  __shared__ __align__(16) unsigned short As[BM*BK];   // 16 KB
  __shared__ __align__(16) unsigned short Bs[BN*BK];   // 16 KB
  int t = threadIdx.x;
  int n0 = blockIdx.x * BN;
  int m0 = blockIdx.y * BM;
  int w = t >> 6, lane = t & 63;
  int wm = w >> 1, wn = w & 1;
  int lrow = lane & 15;
  int cgrp = (lane >> 4) * 16;     // byte col group within 128B row
  int slot = t & 7;                // staging 16B slot within row

  f32x4 acc[4][4];
  #pragma unroll
  for (int i=0;i<4;i++)
    #pragma unroll
    for (int j=0;j<4;j++) acc[i][j] = (f32x4){0.f,0.f,0.f,0.f};

  for (int kk = 0; kk < KTOT; kk += BK){
    __syncthreads();
    if (kk < NF){
      // A self-half: direct global->LDS, source address pre-swizzled
      #pragma unroll
      for (int p = 0; p < 4; p++){
        int flat = p*256 + t;
        int row = flat >> 3;
        const char* g = (const char*)(xb + (size_t)(m0 + row)*NF + kk)
                        + ((slot ^ (row & 7)) << 4);
        gload16(g, (char*)As + (size_t)(flat & ~63)*16, lane);
      }
    } else {
      // A neigh-half: fp8 -> bf16 reg-stage into swizzled LDS position
      #pragma unroll
      for (int p = 0; p < 4; p++){
        int flat = p*256 + t;
        int row = flat >> 3;
        const unsigned char* g = hq + (size_t)(m0 + row)*NF + (kk - NF)
                                 + ((slot ^ (row & 7)) << 3);
        uint2 v = *(const uint2*)g;
        ushort4 lo = dec8(v.x), hi = dec8(v.y);
        char* dstb = (char*)As + (size_t)row*128 + slot*16;
        *(ushort4*)dstb = lo;
        *(ushort4*)(dstb + 8) = hi;
      }
    }
    // B tile: direct global->LDS, swizzled source
    #pragma unroll
    for (int p = 0; p < 4; p++){
      int flat = p*256 + t;
      int row = flat >> 3;
      const char* g = (const char*)(Wt + (size_t)(n0 + row)*KTOT + kk)
                      + ((slot ^ (row & 7)) << 4);
      gload16(g, (char*)Bs + (size_t)(flat & ~63)*16, lane);
    }
    __syncthreads();   // compiler drains vmcnt+lgkmcnt here

    #pragma unroll
    for (int ks = 0; ks < 2; ks++){
      bf16x8 af[4], bfr[4];
      #pragma unroll
      for (int mi=0;mi<4;mi++){
        int row = wm*64 + mi*16 + lrow;
        int cb = (ks*64 + cgrp) ^ ((row & 7) << 4);
        af[mi] = *(const bf16x8*)((const char*)As + (size_t)row*128 + cb);
      }
      #pragma unroll
      for (int ni=0;ni<4;ni++){
        int row = wn*64 + ni*16 + lrow;
        int cb = (ks*64 + cgrp) ^ ((row & 7) << 4);
        bfr[ni] = *(const bf16x8*)((const char*)Bs + (size_t)row*128 + cb);
      }
      #pragma unroll
      for (int mi=0;mi<4;mi++)
        #pragma unroll
        for (int ni=0;ni<4;ni++)
          acc[mi][ni] = __builtin_amdgcn_mfma_f32_16x16x32_bf16(af[mi], bfr[ni], acc[mi][ni], 0, 0, 0);
    }
  }

  #pragma unroll
  for (int ni=0;ni<4;ni++){
    int cn = n0 + wn*64 + ni*16 + lrow;
    float bv = bias[cn];
    #pragma unroll
    for (int mi=0;mi<4;mi++){
      #pragma unroll
      for (int r=0;r<4;r++){
        int rm = m0 + wm*64 + mi*16 + (lane>>4)*4 + r;
        if (rm < M){
          float v = acc[mi][ni][r] + bv;
          out[(size_t)rm*NH + cn] = v > 0.f ? v : 0.f;
        }
      }
    }
  }
}

extern "C" void kernel_launch(void* const* d_in, const int* in_sizes, int n_in,
                              void* d_out, int out_size, void* d_ws, size_t ws_size,
                              hipStream_t stream){
  const float* x      = (const float*)d_in[0];
  const float* Wself  = (const float*)d_in[1];
  const float* Wneigh = (const float*)d_in[2];
  const float* bias   = (const float*)d_in[3];
  const int*   esrc   = (const int*)d_in[4];
  const int*   edst   = (const int*)d_in[5];
  const int nn = in_sizes[0] / NF;   // 100000
  const int ne = in_sizes[4];        // 3200000
  const int mpad = ((nn + BM - 1) / BM) * BM;  // 100096

  // workspace carve-up (~112 MiB; hq aliases bkt; H aliases col -- both dead before use)
  char* w = (char*)d_ws;
  auto alloc = [&](size_t bytes)->char*{
    char* p = w; w += (bytes + 511) & ~size_t(511); return p;
  };
  unsigned short* xb  = (unsigned short*)alloc((size_t)mpad*NF*2); // bf16 x, 51.25 MB
  unsigned char*  xq  = (unsigned char*)alloc((size_t)nn*NF);      // fp8 x row-major, 25.6 MB
  char* hq_bkt        = alloc((size_t)mpad*NF);                    // union: bkt (12.8) / hq (25.6)
  int* col            = (int*)alloc((size_t)ne*4);                 // CSR col 12.8 MB; first 1MB doubles as H
  int* base           = (int*)alloc(((size_t)NBIN*EB + 1)*4);      // scanned hist, 1.05 MB
  int* off            = (int*)alloc((size_t)(nn+1)*4);
  unsigned short* Wt  = (unsigned short*)alloc((size_t)NH*KTOT*2);
  int* partial        = (int*)alloc(4096);
  unsigned int* bkt   = (unsigned int*)hq_bkt;
  unsigned char* hq   = (unsigned char*)hq_bkt;
  int* H              = col;   // H dead after k_scanapply; col written only in k_csr

  const int nH = NBIN*EB;            // 262144
  const int nb = nH / 1024;          // 256

  k_cvt<<<2048 + 512 + 512, 256, 0, stream>>>(x, xb, (unsigned int*)xq, nn*NF/8,
                                              Wself, Wneigh, Wt, edst, H, ne);
  k_partial<<<nb, 256, 0, stream>>>(H, partial, nH);
  k_scanp<<<1, 256, 0, stream>>>(partial, nb);
  k_scanapply<<<nb, 256, 0, stream>>>(H, partial, base, nH, ne);
  k_bscat<<<EB, 256, 0, stream>>>(esrc, edst, base, bkt, ne);
  k_csr<<<NBIN, 256, 0, stream>>>(bkt, base, off, col, nn, ne);
  k_agg<<<(nn + 3)/4, 256, 0, stream>>>((const unsigned int*)xq, off, col, (unsigned int*)hq, nn);
  dim3 gg(NH/BN, mpad/BM);
  k_gemm<<<gg, 256, 0, stream>>>(xb, hq, Wt, bias, (float*)d_out, nn);
}